// Round 2
// baseline (461.903 us; speedup 1.0000x reference)
//
#include <hip/hip_runtime.h>
#include <hip/hip_bf16.h>
#include <stdint.h>

#define NQ 128
#define NLVL 5

typedef float  floatx4 __attribute__((ext_vector_type(4)));
typedef short  short8  __attribute__((ext_vector_type(8)));

__device__ __forceinline__ uint16_t f2bf(float f) {
    uint32_t u = __builtin_bit_cast(uint32_t, f);
    uint32_t r = u + 0x7FFFu + ((u >> 16) & 1u);   // round-to-nearest-even
    return (uint16_t)(r >> 16);
}
__device__ __forceinline__ uint32_t pack2(float a, float b) {
    return (uint32_t)f2bf(a) | ((uint32_t)f2bf(b) << 16);
}
__device__ __forceinline__ float bf2f(uint16_t u) {
    return __builtin_bit_cast(float, (uint32_t)u << 16);
}

// ---------------------------------------------------------------- softmax ----
struct SmParams {
    const float* w[NLVL];
    uint16_t*    smT[NLVL];   // each NQ x C, row-major in o (K-contiguous rows)
    int          C[NLVL];
};

__global__ __launch_bounds__(64) void softmax_kernel(SmParams p) {
    int b   = blockIdx.x;      // 5*128 blocks
    int lvl = b >> 7;
    int o   = b & 127;
    int C   = p.C[lvl];
    const float* w = p.w[lvl];
    int lane = threadIdx.x;    // 64
    float ev[8];
    int nIter = C >> 6;        // C/64 : 1,2,4,8,8
    float mx = -1e30f;
    for (int it = 0; it < nIter; ++it) {
        float z = 10.0f * w[(size_t)(it * 64 + lane) * NQ + o];
        ev[it] = z;
        mx = fmaxf(mx, z);
    }
    #pragma unroll
    for (int s = 32; s; s >>= 1) mx = fmaxf(mx, __shfl_xor(mx, s));
    float sum = 0.f;
    for (int it = 0; it < nIter; ++it) { ev[it] = expf(ev[it] - mx); sum += ev[it]; }
    #pragma unroll
    for (int s = 32; s; s >>= 1) sum += __shfl_xor(sum, s);
    float inv = 1.0f / sum;
    uint16_t* dst = p.smT[lvl] + (size_t)o * C;
    for (int it = 0; it < nIter; ++it) dst[it * 64 + lane] = f2bf(ev[it] * inv);
}

// ------------------------------------------------------------------- gram ----
// G(n,c,c') = sum_h M(n,c,h) * M(n,c',h)  for levels 0 (C=64) and 1 (C=128).
// Split-K over h; one LDS tile serves as BOTH MFMA operands (G symmetric-product:
// A-frag of row-tile == B-frag of col-tile, identical ds_read layout).
struct GramParams { const float* x0; const float* x1; float* g0; float* g1; };

template<int C, int HW, int NS>
__device__ __forceinline__ void gram_body(const float* __restrict__ xb,
                                          float* __restrict__ gb,
                                          int h0, short* lds) {
    constexpr int RF   = C / 64;   // row frags per wave (1 / 2)
    constexpr int CF   = C / 16;   // col frags total    (4 / 8)
    constexpr int PASS = C / 16;   // float4 loads per thread per step
    constexpr int STR  = 72;       // shorts per row: 64 h-values + 8 pad (144B)

    int t    = threadIdx.x;
    int wv   = t >> 6, lane = t & 63, m = lane & 15, kg = lane >> 4;
    int rrow = t >> 4;             // staging row slot within a 16-row pass
    int rcol = (t & 15) * 4;       // h offset (floats); 16 lanes = 256B contiguous
    const float* src = xb + (size_t)rrow * HW + rcol + h0;

    floatx4 acc[RF][CF];
    floatx4 zero = {0.f, 0.f, 0.f, 0.f};
    #pragma unroll
    for (int rf = 0; rf < RF; ++rf)
        #pragma unroll
        for (int cf = 0; cf < CF; ++cf) acc[rf][cf] = zero;

    // prologue: stage step 0
    float4 pf[PASS];
    #pragma unroll
    for (int p = 0; p < PASS; ++p) pf[p] = *(const float4*)(src + (size_t)p * 16 * HW);
    #pragma unroll
    for (int p = 0; p < PASS; ++p) {
        uint2 pk = { pack2(pf[p].x, pf[p].y), pack2(pf[p].z, pf[p].w) };
        *(uint2*)&lds[(p * 16 + rrow) * STR + rcol] = pk;
    }

    int cur = 0;
    for (int s = 0; s < NS; ++s) {
        if (s + 1 < NS) {           // issue next step's loads early (latency hides under MFMA)
            const float* s2 = src + (s + 1) * 64;
            #pragma unroll
            for (int p = 0; p < PASS; ++p) pf[p] = *(const float4*)(s2 + (size_t)p * 16 * HW);
        }
        __syncthreads();            // buf[cur] writes visible; prior reads of buf[cur^1] done
        const short* bc = lds + cur * (C * STR);
        #pragma unroll
        for (int ksl = 0; ksl < 2; ++ksl) {
            short8 fr[CF], af[RF];
            #pragma unroll
            for (int f = 0; f < CF; ++f)
                fr[f] = *(const short8*)&bc[(f * 16 + m) * STR + ksl * 32 + kg * 8];
            #pragma unroll
            for (int rf = 0; rf < RF; ++rf)
                af[rf] = *(const short8*)&bc[((wv * RF + rf) * 16 + m) * STR + ksl * 32 + kg * 8];
            #pragma unroll
            for (int rf = 0; rf < RF; ++rf)
                #pragma unroll
                for (int cf = 0; cf < CF; ++cf)
                    acc[rf][cf] = __builtin_amdgcn_mfma_f32_16x16x32_bf16(
                        af[rf], fr[cf], acc[rf][cf], 0, 0, 0);
        }
        if (s + 1 < NS) {
            short* bn = lds + (cur ^ 1) * (C * STR);
            #pragma unroll
            for (int p = 0; p < PASS; ++p) {
                uint2 pk = { pack2(pf[p].x, pf[p].y), pack2(pf[p].z, pf[p].w) };
                *(uint2*)&bn[(p * 16 + rrow) * STR + rcol] = pk;
            }
        }
        cur ^= 1;
    }

    // epilogue: C/D layout col=lane&15, row=kg*4+r
    #pragma unroll
    for (int rf = 0; rf < RF; ++rf) {
        int row0 = (wv * RF + rf) * 16 + kg * 4;
        #pragma unroll
        for (int cf = 0; cf < CF; ++cf) {
            int col = cf * 16 + m;
            #pragma unroll
            for (int r = 0; r < 4; ++r)
                atomicAdd(&gb[(size_t)(row0 + r) * C + col], acc[rf][cf][r]);
        }
    }
}

__global__ __launch_bounds__(256) void gram_kernel(GramParams p) {
    __shared__ __align__(16) short lds[2 * 128 * 72];   // 36,864 B (dbuf, C=128 sized)
    int b = blockIdx.x;
    if (b < 512) {                       // level 0: 8n x 64 chunks x 1024h (16 steps, 256KB)
        int n = b >> 6, ch = b & 63;
        gram_body<64, 65536, 16>(p.x0 + (size_t)n * 64 * 65536,
                                 p.g0 + (size_t)n * 64 * 64, ch * 1024, lds);
    } else {                             // level 1: 8n x 32 chunks x 512h (8 steps, 256KB)
        int b2 = b - 512;
        int n = b2 >> 5, ch = b2 & 31;
        gram_body<128, 16384, 8>(p.x1 + (size_t)n * 128 * 16384,
                                 p.g1 + (size_t)n * 128 * 128, ch * 512, lds);
    }
}

// ------------------------------------------------------------------- sgs -----
// quad(n,o) = S_o^T G S_o  for levels 0/1. G staged to LDS as bf16 hi/lo split
// (two MFMAs) so accuracy matches the direct bf16 path.
// NOTE: LDS row stride here must hold a FULL G row (K = C values), unlike gram
// where a row is only 64 h-values.  STR = C + 8 keeps 16B row alignment.
struct SgsParams {
    const float* g0; const float* g1;
    const uint16_t* smT0; const uint16_t* smT1;
    float* quad;
};

template<int C>
__device__ __forceinline__ void sgs_body(const float* __restrict__ g,
                                         const uint16_t* __restrict__ smT,
                                         float* __restrict__ qdst, short* Gt) {
    constexpr int RF  = C / 64;
    constexpr int KSL = C / 32;
    constexpr int STR = C + 8;      // 72 (C=64) / 136 (C=128); rows 16B-aligned
    int t = threadIdx.x;
    short* Ghi = Gt;
    short* Glo = Gt + C * STR;
    for (int i = t; i < C * C / 4; i += 256) {
        int row = i / (C / 4);
        int c4  = (i % (C / 4)) * 4;
        float4 v = *(const float4*)(g + (size_t)row * C + c4);
        uint16_t h0 = f2bf(v.x), h1 = f2bf(v.y), h2 = f2bf(v.z), h3 = f2bf(v.w);
        uint2 ph = { (uint32_t)h0 | ((uint32_t)h1 << 16),
                     (uint32_t)h2 | ((uint32_t)h3 << 16) };
        uint2 pl = { pack2(v.x - bf2f(h0), v.y - bf2f(h1)),
                     pack2(v.z - bf2f(h2), v.w - bf2f(h3)) };
        *(uint2*)&Ghi[row * STR + c4] = ph;
        *(uint2*)&Glo[row * STR + c4] = pl;
    }
    __syncthreads();
    int wv = t >> 6, lane = t & 63, m = lane & 15, kg = lane >> 4;
    floatx4 acc[RF][8];
    floatx4 zero = {0.f, 0.f, 0.f, 0.f};
    #pragma unroll
    for (int rf = 0; rf < RF; ++rf)
        #pragma unroll
        for (int ot = 0; ot < 8; ++ot) acc[rf][ot] = zero;

    #pragma unroll
    for (int ksl = 0; ksl < KSL; ++ksl) {
        short8 bf[8];
        #pragma unroll
        for (int ot = 0; ot < 8; ++ot)   // B-frag straight from global smT (L2-hot)
            bf[ot] = *(const short8*)(smT + (size_t)(ot * 16 + m) * C + ksl * 32 + kg * 8);
        #pragma unroll
        for (int rf = 0; rf < RF; ++rf) {
            int roff = ((wv * RF + rf) * 16 + m) * STR + ksl * 32 + kg * 8;
            short8 ah = *(const short8*)&Ghi[roff];
            short8 al = *(const short8*)&Glo[roff];
            #pragma unroll
            for (int ot = 0; ot < 8; ++ot) {
                acc[rf][ot] = __builtin_amdgcn_mfma_f32_16x16x32_bf16(ah, bf[ot], acc[rf][ot], 0, 0, 0);
                acc[rf][ot] = __builtin_amdgcn_mfma_f32_16x16x32_bf16(al, bf[ot], acc[rf][ot], 0, 0, 0);
            }
        }
    }
    #pragma unroll
    for (int ot = 0; ot < 8; ++ot) {
        float part = 0.f;
        #pragma unroll
        for (int rf = 0; rf < RF; ++rf) {
            int c0 = (wv * RF + rf) * 16 + kg * 4;
            #pragma unroll
            for (int r = 0; r < 4; ++r) {
                float sv = bf2f(smT[(size_t)(ot * 16 + m) * C + c0 + r]);
                part = fmaf(sv, acc[rf][ot][r], part);
            }
        }
        part += __shfl_xor(part, 16);
        part += __shfl_xor(part, 32);
        if (lane < 16) atomicAdd(qdst + (size_t)(ot * 16 + lane) * 16, part);
    }
}

__global__ __launch_bounds__(256) void sgs_kernel(SgsParams p) {
    __shared__ __align__(16) short Gt[2 * 128 * 136];   // 69,632 B (C=128 hi+lo)
    int b = blockIdx.x, lvl = b >> 3, n = b & 7;
    if (lvl == 0)
        sgs_body<64>(p.g0 + (size_t)n * 64 * 64, p.smT0,
                     p.quad + (size_t)n * 128 * 16, Gt);
    else
        sgs_body<128>(p.g1 + (size_t)n * 128 * 128, p.smT1,
                      p.quad + (size_t)(8 + n) * 128 * 16, Gt);
}

// ------------------------------------------------------- quad (levels 2-4) ---
struct QuadParams {
    const float*    x[NLVL];
    const uint16_t* smT[NLVL];
    float*          quad;          // padded stride 16 floats
    int             C[NLVL];
    int             HW[NLVL];
    int             blk_base[NLVL];
};

__global__ __launch_bounds__(256) void quad_kernel(QuadParams p) {
    __shared__ __align__(16) short At[64 * 40];
    __shared__ __align__(16) short Bt[128 * 40];

    int bid = blockIdx.x;
    int lvl = 0;
    #pragma unroll
    for (int l = 1; l < 3; ++l) if (bid >= p.blk_base[l]) lvl = l;
    int rel = bid - p.blk_base[lvl];
    int n   = rel & 7;
    int ht  = rel >> 3;
    int C   = p.C[lvl];
    int HW  = p.HW[lvl];
    int h0  = ht * 64;

    const float*    xb  = p.x[lvl] + (size_t)n * C * HW + h0;
    const uint16_t* smT = p.smT[lvl];

    int t    = threadIdx.x;
    int wave = t >> 6;
    int lane = t & 63;
    int m    = lane & 15;
    int kg   = lane >> 4;

    floatx4 acc[4][2];
    floatx4 zero = {0.f, 0.f, 0.f, 0.f};
    #pragma unroll
    for (int i = 0; i < 4; ++i)
        #pragma unroll
        for (int j = 0; j < 2; ++j) acc[i][j] = zero;

    int c_l = (t & 15) * 2;
    int h_l = (t >> 4) * 4;

    for (int c0 = 0; c0 < C; c0 += 32) {
        const float* s1 = xb + (size_t)(c0 + c_l) * HW + h_l;
        float4 a4 = *(const float4*)s1;
        float4 b4 = *(const float4*)(s1 + HW);
        #pragma unroll
        for (int j = 0; j < 4; ++j) {
            uint32_t pk = (uint32_t)f2bf(((const float*)&a4)[j]) |
                          ((uint32_t)f2bf(((const float*)&b4)[j]) << 16);
            *(uint32_t*)&At[(h_l + j) * 40 + c_l] = pk;
        }
        #pragma unroll
        for (int it = 0; it < 2; ++it) {
            int idx  = it * 256 + t;
            int o    = idx >> 2;
            int part = idx & 3;
            uint4 v = *(const uint4*)(smT + (size_t)o * C + c0 + part * 8);
            *(uint4*)&Bt[o * 40 + part * 8] = v;
        }
        __syncthreads();

        short8 af[4];
        #pragma unroll
        for (int mt = 0; mt < 4; ++mt)
            af[mt] = *(const short8*)&At[(mt * 16 + m) * 40 + kg * 8];
        short8 bfr[2];
        #pragma unroll
        for (int ot = 0; ot < 2; ++ot)
            bfr[ot] = *(const short8*)&Bt[((wave * 2 + ot) * 16 + m) * 40 + kg * 8];
        #pragma unroll
        for (int mt = 0; mt < 4; ++mt)
            #pragma unroll
            for (int ot = 0; ot < 2; ++ot)
                acc[mt][ot] = __builtin_amdgcn_mfma_f32_16x16x32_bf16(
                    af[mt], bfr[ot], acc[mt][ot], 0, 0, 0);
        __syncthreads();
    }

    float* qbase = p.quad + (size_t)((lvl + 2) * 8 + n) * 128 * 16;
    #pragma unroll
    for (int ot = 0; ot < 2; ++ot) {
        float part = 0.f;
        #pragma unroll
        for (int mt = 0; mt < 4; ++mt)
            #pragma unroll
            for (int r = 0; r < 4; ++r) {
                float v = acc[mt][ot][r];
                part = fmaf(v, v, part);
            }
        part += __shfl_xor(part, 16);
        part += __shfl_xor(part, 32);
        if (lane < 16) {
            int o = (wave * 2 + ot) * 16 + lane;
            atomicAdd(qbase + (size_t)o * 16, part);
        }
    }
}

// ------------------------------------------------------------------- head ----
__device__ __forceinline__ float block_sum512(float v, float* red8, int t) {
    #pragma unroll
    for (int s = 32; s; s >>= 1) v += __shfl_xor(v, s);
    __syncthreads();
    if ((t & 63) == 0) red8[t >> 6] = v;
    __syncthreads();
    float tot = 0.f;
    #pragma unroll
    for (int i = 0; i < 8; ++i) tot += red8[i];
    return tot;
}

__global__ __launch_bounds__(512) void head_kernel(
    const float* __restrict__ quad,
    const float* __restrict__ fc1_w, const float* __restrict__ fc1_b,
    const float* __restrict__ fc2_w, const float* __restrict__ fc2_b,
    const float* __restrict__ fc3_w, const float* __restrict__ fc3_b,
    float* __restrict__ out) {
    __shared__ float feat[640];
    __shared__ float hbuf[512];
    __shared__ float red8[8];
    __shared__ float stats[10];
    int n = blockIdx.x;
    int t = threadIdx.x;

    for (int idx = t; idx < 640; idx += 512) {
        int lvl = idx >> 7, o = idx & 127;
        feat[idx] = quad[((size_t)(lvl * 8 + n) * 128 + o) * 16];
    }
    __syncthreads();
    if (t < 5) {
        float s = 0.f;
        for (int i = 0; i < 128; ++i) s += feat[t * 128 + i];
        float mean = s * (1.f / 128.f);
        float v = 0.f;
        for (int i = 0; i < 128; ++i) { float d = feat[t * 128 + i] - mean; v += d * d; }
        stats[t]     = mean;
        stats[5 + t] = sqrtf(v * (1.f / 127.f)) + 1e-8f;
    }
    __syncthreads();
    for (int idx = t; idx < 640; idx += 512) {
        int lvl = idx >> 7;
        feat[idx] = (feat[idx] - stats[lvl]) / stats[5 + lvl];
    }
    __syncthreads();

    float acc = fc1_b[t];
    #pragma unroll 8
    for (int i = 0; i < 640; ++i) acc = fmaf(feat[i], fc1_w[(size_t)i * 512 + t], acc);
    float mean = block_sum512(acc, red8, t) * (1.f / 512.f);
    float d    = acc - mean;
    float var  = block_sum512(d * d, red8, t) * (1.f / 511.f);
    float nv   = d / (sqrtf(var) + 1e-8f);
    __syncthreads();
    hbuf[t] = nv > 0.f ? nv : 0.01f * nv;
    __syncthreads();

    float acc2 = fc2_b[t];
    #pragma unroll 8
    for (int i = 0; i < 512; ++i) acc2 = fmaf(hbuf[i], fc2_w[(size_t)i * 512 + t], acc2);
    mean = block_sum512(acc2, red8, t) * (1.f / 512.f);
    d    = acc2 - mean;
    var  = block_sum512(d * d, red8, t) * (1.f / 511.f);
    nv   = d / (sqrtf(var) + 1e-8f);
    __syncthreads();
    hbuf[t] = nv > 0.f ? nv : 0.01f * nv;
    __syncthreads();

    if (t < 128) {
        float acc3 = fc3_b[t];
        #pragma unroll 8
        for (int i = 0; i < 512; ++i) acc3 = fmaf(hbuf[i], fc3_w[(size_t)i * 128 + t], acc3);
        out[(size_t)n * 128 + t] = acc3;
    }
}

// ----------------------------------------------------------------- launch ----
extern "C" void kernel_launch(void* const* d_in, const int* in_sizes, int n_in,
                              void* d_out, int out_size, void* d_ws, size_t ws_size,
                              hipStream_t stream) {
    static const int Cs[NLVL]   = {64, 128, 256, 512, 512};
    static const int RESs[NLVL] = {256, 128, 64, 32, 16};

    const float* x[NLVL];
    const float* w[NLVL];
    for (int i = 0; i < NLVL; ++i) {
        x[i] = (const float*)d_in[2 * i];
        w[i] = (const float*)d_in[2 * i + 1];
    }
    const float* fc1_w = (const float*)d_in[10];
    const float* fc1_b = (const float*)d_in[11];
    const float* fc2_w = (const float*)d_in[12];
    const float* fc2_b = (const float*)d_in[13];
    const float* fc3_w = (const float*)d_in[14];
    const float* fc3_b = (const float*)d_in[15];

    // workspace: smT (bf16) | quad padded fp32 | G0 fp32 | G1 fp32
    uint16_t* smT_base = (uint16_t*)d_ws;
    int smOff[NLVL];
    int off = 0;
    for (int i = 0; i < NLVL; ++i) { smOff[i] = off; off += Cs[i] * NQ; }
    size_t smBytes = (size_t)off * sizeof(uint16_t);         // 376,832 (16B mult)
    float* quad = (float*)((char*)d_ws + smBytes);
    size_t quadFloats = (size_t)NLVL * 8 * NQ * 16;          // 81,920
    float* g0 = quad + quadFloats;
    float* g1 = g0 + (size_t)8 * 64 * 64;
    size_t zeroBytes = (quadFloats + (size_t)8 * 64 * 64 + (size_t)8 * 128 * 128) * sizeof(float);

    SmParams sp;
    for (int i = 0; i < NLVL; ++i) {
        sp.w[i]   = w[i];
        sp.smT[i] = smT_base + smOff[i];
        sp.C[i]   = Cs[i];
    }
    softmax_kernel<<<NLVL * NQ, 64, 0, stream>>>(sp);

    hipMemsetAsync(quad, 0, zeroBytes, stream);

    GramParams gp;
    gp.x0 = x[0]; gp.x1 = x[1]; gp.g0 = g0; gp.g1 = g1;
    gram_kernel<<<768, 256, 0, stream>>>(gp);

    QuadParams qp;
    int base = 0;
    for (int i = 0; i < 3; ++i) {
        int lvl = i + 2;
        qp.x[i]   = x[lvl];
        qp.smT[i] = smT_base + smOff[lvl];
        qp.C[i]   = Cs[lvl];
        qp.HW[i]  = RESs[lvl] * RESs[lvl];
        qp.blk_base[i] = base;
        base += (RESs[lvl] * RESs[lvl] / 64) * 8;
    }
    for (int i = 3; i < NLVL; ++i) {
        qp.x[i] = nullptr; qp.smT[i] = nullptr;
        qp.C[i] = 0; qp.HW[i] = 0; qp.blk_base[i] = 0x7fffffff;
    }
    qp.quad = quad;
    quad_kernel<<<base, 256, 0, stream>>>(qp);   // base == 672

    SgsParams ssp;
    ssp.g0 = g0; ssp.g1 = g1;
    ssp.smT0 = smT_base + smOff[0];
    ssp.smT1 = smT_base + smOff[1];
    ssp.quad = quad;
    sgs_kernel<<<16, 256, 0, stream>>>(ssp);

    head_kernel<<<8, 512, 0, stream>>>(quad, fc1_w, fc1_b, fc2_w, fc2_b,
                                       fc3_w, fc3_b, (float*)d_out);
}

// Round 4
// 391.115 us; speedup vs baseline: 1.1810x; 1.1810x over previous
//
#include <hip/hip_runtime.h>
#include <hip/hip_bf16.h>
#include <stdint.h>

#define NQ 128
#define NLVL 5

typedef float  floatx4 __attribute__((ext_vector_type(4)));
typedef short  short8  __attribute__((ext_vector_type(8)));

__device__ __forceinline__ uint16_t f2bf(float f) {
    uint32_t u = __builtin_bit_cast(uint32_t, f);
    uint32_t r = u + 0x7FFFu + ((u >> 16) & 1u);   // round-to-nearest-even
    return (uint16_t)(r >> 16);
}
__device__ __forceinline__ uint32_t pack2(float a, float b) {
    return (uint32_t)f2bf(a) | ((uint32_t)f2bf(b) << 16);
}
__device__ __forceinline__ float bf2f(uint16_t u) {
    return __builtin_bit_cast(float, (uint32_t)u << 16);
}

// ---------------------------------------------------------------- softmax ----
struct SmParams {
    const float* w[NLVL];
    uint16_t*    smT[NLVL];   // each NQ x C, row-major in o (K-contiguous rows)
    int          C[NLVL];
};

__global__ __launch_bounds__(64) void softmax_kernel(SmParams p) {
    int b   = blockIdx.x;      // 5*128 blocks
    int lvl = b >> 7;
    int o   = b & 127;
    int C   = p.C[lvl];
    const float* w = p.w[lvl];
    int lane = threadIdx.x;    // 64
    float ev[8];
    int nIter = C >> 6;        // C/64 : 1,2,4,8,8
    float mx = -1e30f;
    for (int it = 0; it < nIter; ++it) {
        float z = 10.0f * w[(size_t)(it * 64 + lane) * NQ + o];
        ev[it] = z;
        mx = fmaxf(mx, z);
    }
    #pragma unroll
    for (int s = 32; s; s >>= 1) mx = fmaxf(mx, __shfl_xor(mx, s));
    float sum = 0.f;
    for (int it = 0; it < nIter; ++it) { ev[it] = expf(ev[it] - mx); sum += ev[it]; }
    #pragma unroll
    for (int s = 32; s; s >>= 1) sum += __shfl_xor(sum, s);
    float inv = 1.0f / sum;
    uint16_t* dst = p.smT[lvl] + (size_t)o * C;
    for (int it = 0; it < nIter; ++it) dst[it * 64 + lane] = f2bf(ev[it] * inv);
}

// ------------------------------------------------------------------- gram ----
// G(n,c,c') = sum_h M(n,c,h) * M(n,c',h)  for levels 0 (C=64) and 1 (C=128).
// Split-K over h; one LDS tile serves as BOTH MFMA operands (G symmetric-product:
// A-frag of row-tile == B-frag of col-tile, identical ds_read layout).
struct GramParams { const float* x0; const float* x1; float* g0; float* g1; };

template<int C, int HW, int NS>
__device__ __forceinline__ void gram_body(const float* __restrict__ xb,
                                          float* __restrict__ gb,
                                          int h0, short* lds) {
    constexpr int RF   = C / 64;   // row frags per wave (1 / 2)
    constexpr int CF   = C / 16;   // col frags total    (4 / 8)
    constexpr int PASS = C / 16;   // float4 loads per thread per step
    constexpr int STR  = 72;       // shorts per row: 64 h-values + 8 pad (144B)

    int t    = threadIdx.x;
    int wv   = t >> 6, lane = t & 63, m = lane & 15, kg = lane >> 4;
    int rrow = t >> 4;             // staging row slot within a 16-row pass
    int rcol = (t & 15) * 4;       // h offset (floats); 16 lanes = 256B contiguous
    const float* src = xb + (size_t)rrow * HW + rcol + h0;

    floatx4 acc[RF][CF];
    floatx4 zero = {0.f, 0.f, 0.f, 0.f};
    #pragma unroll
    for (int rf = 0; rf < RF; ++rf)
        #pragma unroll
        for (int cf = 0; cf < CF; ++cf) acc[rf][cf] = zero;

    // prologue: stage step 0
    float4 pf[PASS];
    #pragma unroll
    for (int p = 0; p < PASS; ++p) pf[p] = *(const float4*)(src + (size_t)p * 16 * HW);
    #pragma unroll
    for (int p = 0; p < PASS; ++p) {
        uint2 pk = { pack2(pf[p].x, pf[p].y), pack2(pf[p].z, pf[p].w) };
        *(uint2*)&lds[(p * 16 + rrow) * STR + rcol] = pk;
    }

    int cur = 0;
    for (int s = 0; s < NS; ++s) {
        if (s + 1 < NS) {           // issue next step's loads early (latency hides under MFMA)
            const float* s2 = src + (s + 1) * 64;
            #pragma unroll
            for (int p = 0; p < PASS; ++p) pf[p] = *(const float4*)(s2 + (size_t)p * 16 * HW);
        }
        __syncthreads();            // buf[cur] writes visible; prior reads of buf[cur^1] done
        const short* bc = lds + cur * (C * STR);
        #pragma unroll
        for (int ksl = 0; ksl < 2; ++ksl) {
            short8 fr[CF], af[RF];
            #pragma unroll
            for (int f = 0; f < CF; ++f)
                fr[f] = *(const short8*)&bc[(f * 16 + m) * STR + ksl * 32 + kg * 8];
            #pragma unroll
            for (int rf = 0; rf < RF; ++rf)
                af[rf] = *(const short8*)&bc[((wv * RF + rf) * 16 + m) * STR + ksl * 32 + kg * 8];
            #pragma unroll
            for (int rf = 0; rf < RF; ++rf)
                #pragma unroll
                for (int cf = 0; cf < CF; ++cf)
                    acc[rf][cf] = __builtin_amdgcn_mfma_f32_16x16x32_bf16(
                        af[rf], fr[cf], acc[rf][cf], 0, 0, 0);
        }
        if (s + 1 < NS) {
            short* bn = lds + (cur ^ 1) * (C * STR);
            #pragma unroll
            for (int p = 0; p < PASS; ++p) {
                uint2 pk = { pack2(pf[p].x, pf[p].y), pack2(pf[p].z, pf[p].w) };
                *(uint2*)&bn[(p * 16 + rrow) * STR + rcol] = pk;
            }
        }
        cur ^= 1;
    }

    // epilogue: C/D layout col=lane&15, row=kg*4+r
    #pragma unroll
    for (int rf = 0; rf < RF; ++rf) {
        int row0 = (wv * RF + rf) * 16 + kg * 4;
        #pragma unroll
        for (int cf = 0; cf < CF; ++cf) {
            int col = cf * 16 + m;
            #pragma unroll
            for (int r = 0; r < 4; ++r)
                atomicAdd(&gb[(size_t)(row0 + r) * C + col], acc[rf][cf][r]);
        }
    }
}

__global__ __launch_bounds__(256) void gram_kernel(GramParams p) {
    __shared__ __align__(16) short lds[2 * 128 * 72];   // 36,864 B (dbuf, C=128 sized)
    int b = blockIdx.x;
    if (b < 512) {                       // level 0: 8n x 64 chunks x 1024h (16 steps, 256KB)
        int n = b >> 6, ch = b & 63;
        gram_body<64, 65536, 16>(p.x0 + (size_t)n * 64 * 65536,
                                 p.g0 + (size_t)n * 64 * 64, ch * 1024, lds);
    } else {                             // level 1: 8n x 32 chunks x 512h (8 steps, 256KB)
        int b2 = b - 512;
        int n = b2 >> 5, ch = b2 & 31;
        gram_body<128, 16384, 8>(p.x1 + (size_t)n * 128 * 16384,
                                 p.g1 + (size_t)n * 128 * 128, ch * 512, lds);
    }
}

// ------------------------------------------------------------------- sgs -----
// quad(n,o) = S_o^T G S_o  for levels 0/1. G staged to LDS as bf16 hi/lo split
// (two MFMAs) so accuracy matches the direct bf16 path.
// NOTE: LDS row stride here must hold a FULL G row (K = C values), unlike gram
// where a row is only 64 h-values.  STR = C + 8 keeps 16B row alignment.
struct SgsParams {
    const float* g0; const float* g1;
    const uint16_t* smT0; const uint16_t* smT1;
    float* quad;
};

template<int C>
__device__ __forceinline__ void sgs_body(const float* __restrict__ g,
                                         const uint16_t* __restrict__ smT,
                                         float* __restrict__ qdst, short* Gt) {
    constexpr int RF  = C / 64;
    constexpr int KSL = C / 32;
    constexpr int STR = C + 8;      // 72 (C=64) / 136 (C=128); rows 16B-aligned
    int t = threadIdx.x;
    short* Ghi = Gt;
    short* Glo = Gt + C * STR;
    for (int i = t; i < C * C / 4; i += 256) {
        int row = i / (C / 4);
        int c4  = (i % (C / 4)) * 4;
        float4 v = *(const float4*)(g + (size_t)row * C + c4);
        uint16_t h0 = f2bf(v.x), h1 = f2bf(v.y), h2 = f2bf(v.z), h3 = f2bf(v.w);
        uint2 ph = { (uint32_t)h0 | ((uint32_t)h1 << 16),
                     (uint32_t)h2 | ((uint32_t)h3 << 16) };
        uint2 pl = { pack2(v.x - bf2f(h0), v.y - bf2f(h1)),
                     pack2(v.z - bf2f(h2), v.w - bf2f(h3)) };
        *(uint2*)&Ghi[row * STR + c4] = ph;
        *(uint2*)&Glo[row * STR + c4] = pl;
    }
    __syncthreads();
    int wv = t >> 6, lane = t & 63, m = lane & 15, kg = lane >> 4;
    floatx4 acc[RF][8];
    floatx4 zero = {0.f, 0.f, 0.f, 0.f};
    #pragma unroll
    for (int rf = 0; rf < RF; ++rf)
        #pragma unroll
        for (int ot = 0; ot < 8; ++ot) acc[rf][ot] = zero;

    #pragma unroll
    for (int ksl = 0; ksl < KSL; ++ksl) {
        short8 bf[8];
        #pragma unroll
        for (int ot = 0; ot < 8; ++ot)   // B-frag straight from global smT (L2-hot)
            bf[ot] = *(const short8*)(smT + (size_t)(ot * 16 + m) * C + ksl * 32 + kg * 8);
        #pragma unroll
        for (int rf = 0; rf < RF; ++rf) {
            int roff = ((wv * RF + rf) * 16 + m) * STR + ksl * 32 + kg * 8;
            short8 ah = *(const short8*)&Ghi[roff];
            short8 al = *(const short8*)&Glo[roff];
            #pragma unroll
            for (int ot = 0; ot < 8; ++ot) {
                acc[rf][ot] = __builtin_amdgcn_mfma_f32_16x16x32_bf16(ah, bf[ot], acc[rf][ot], 0, 0, 0);
                acc[rf][ot] = __builtin_amdgcn_mfma_f32_16x16x32_bf16(al, bf[ot], acc[rf][ot], 0, 0, 0);
            }
        }
    }
    #pragma unroll
    for (int ot = 0; ot < 8; ++ot) {
        float part = 0.f;
        #pragma unroll
        for (int rf = 0; rf < RF; ++rf) {
            int c0 = (wv * RF + rf) * 16 + kg * 4;
            #pragma unroll
            for (int r = 0; r < 4; ++r) {
                float sv = bf2f(smT[(size_t)(ot * 16 + m) * C + c0 + r]);
                part = fmaf(sv, acc[rf][ot][r], part);
            }
        }
        part += __shfl_xor(part, 16);
        part += __shfl_xor(part, 32);
        if (lane < 16) atomicAdd(qdst + (size_t)(ot * 16 + lane) * 16, part);
    }
}

__global__ __launch_bounds__(256) void sgs_kernel(SgsParams p) {
    __shared__ __align__(16) short Gt[2 * 128 * 136];   // 69,632 B (C=128 hi+lo)
    int b = blockIdx.x, lvl = b >> 3, n = b & 7;
    if (lvl == 0)
        sgs_body<64>(p.g0 + (size_t)n * 64 * 64, p.smT0,
                     p.quad + (size_t)n * 128 * 16, Gt);
    else
        sgs_body<128>(p.g1 + (size_t)n * 128 * 128, p.smT1,
                      p.quad + (size_t)(8 + n) * 128 * 16, Gt);
}

// ------------------------------------------------------- quad (levels 2-4) ---
struct QuadParams {
    const float*    x[NLVL];
    const uint16_t* smT[NLVL];
    float*          quad;          // padded stride 16 floats
    int             C[NLVL];
    int             HW[NLVL];
    int             blk_base[NLVL];
};

__global__ __launch_bounds__(256) void quad_kernel(QuadParams p) {
    __shared__ __align__(16) short At[64 * 40];
    __shared__ __align__(16) short Bt[128 * 40];

    int bid = blockIdx.x;
    int lvl = 0;
    #pragma unroll
    for (int l = 1; l < 3; ++l) if (bid >= p.blk_base[l]) lvl = l;
    int rel = bid - p.blk_base[lvl];
    int n   = rel & 7;
    int ht  = rel >> 3;
    int C   = p.C[lvl];
    int HW  = p.HW[lvl];
    int h0  = ht * 64;

    const float*    xb  = p.x[lvl] + (size_t)n * C * HW + h0;
    const uint16_t* smT = p.smT[lvl];

    int t    = threadIdx.x;
    int wave = t >> 6;
    int lane = t & 63;
    int m    = lane & 15;
    int kg   = lane >> 4;

    floatx4 acc[4][2];
    floatx4 zero = {0.f, 0.f, 0.f, 0.f};
    #pragma unroll
    for (int i = 0; i < 4; ++i)
        #pragma unroll
        for (int j = 0; j < 2; ++j) acc[i][j] = zero;

    int c_l = (t & 15) * 2;
    int h_l = (t >> 4) * 4;

    for (int c0 = 0; c0 < C; c0 += 32) {
        const float* s1 = xb + (size_t)(c0 + c_l) * HW + h_l;
        float4 a4 = *(const float4*)s1;
        float4 b4 = *(const float4*)(s1 + HW);
        #pragma unroll
        for (int j = 0; j < 4; ++j) {
            uint32_t pk = (uint32_t)f2bf(((const float*)&a4)[j]) |
                          ((uint32_t)f2bf(((const float*)&b4)[j]) << 16);
            *(uint32_t*)&At[(h_l + j) * 40 + c_l] = pk;
        }
        #pragma unroll
        for (int it = 0; it < 2; ++it) {
            int idx  = it * 256 + t;
            int o    = idx >> 2;
            int part = idx & 3;
            uint4 v = *(const uint4*)(smT + (size_t)o * C + c0 + part * 8);
            *(uint4*)&Bt[o * 40 + part * 8] = v;
        }
        __syncthreads();

        short8 af[4];
        #pragma unroll
        for (int mt = 0; mt < 4; ++mt)
            af[mt] = *(const short8*)&At[(mt * 16 + m) * 40 + kg * 8];
        short8 bfr[2];
        #pragma unroll
        for (int ot = 0; ot < 2; ++ot)
            bfr[ot] = *(const short8*)&Bt[((wave * 2 + ot) * 16 + m) * 40 + kg * 8];
        #pragma unroll
        for (int mt = 0; mt < 4; ++mt)
            #pragma unroll
            for (int ot = 0; ot < 2; ++ot)
                acc[mt][ot] = __builtin_amdgcn_mfma_f32_16x16x32_bf16(
                    af[mt], bfr[ot], acc[mt][ot], 0, 0, 0);
        __syncthreads();
    }

    float* qbase = p.quad + (size_t)((lvl + 2) * 8 + n) * 128 * 16;
    #pragma unroll
    for (int ot = 0; ot < 2; ++ot) {
        float part = 0.f;
        #pragma unroll
        for (int mt = 0; mt < 4; ++mt)
            #pragma unroll
            for (int r = 0; r < 4; ++r) {
                float v = acc[mt][ot][r];
                part = fmaf(v, v, part);
            }
        part += __shfl_xor(part, 16);
        part += __shfl_xor(part, 32);
        if (lane < 16) {
            int o = (wave * 2 + ot) * 16 + lane;
            atomicAdd(qbase + (size_t)o * 16, part);
        }
    }
}

// ------------------------------------------------------------- head (split) --
// 3 kernels, layer boundaries provide the syncs. Norm stats recomputed
// redundantly per block (cheap vs a dedicated kernel + launch).

// fc1: 64 blocks = 8 samples x 8 output-chunks of 64.  Block also does the
// per-level feat norm from the quad accumulator.
__global__ __launch_bounds__(256) void hfc1_kernel(
    const float* __restrict__ quad, const float* __restrict__ w,
    const float* __restrict__ b, float* __restrict__ h1) {
    __shared__ float feat[640];
    __shared__ float stats[10];
    __shared__ float part[256];
    int blk = blockIdx.x;
    int n = blk >> 3, c8 = blk & 7;     // c8 == blk%8 -> same-chunk blocks share XCD L2
    int t = threadIdx.x;
    for (int idx = t; idx < 640; idx += 256) {
        int L = idx >> 7, o = idx & 127;
        feat[idx] = quad[((size_t)(L * 8 + n) * 128 + o) * 16];
    }
    __syncthreads();
    int wv = t >> 6, lane = t & 63;
    for (int L = wv; L < 5; L += 4) {          // wave w handles level w (+ wave0: level4)
        float a = feat[L * 128 + lane], c = feat[L * 128 + 64 + lane];
        float s = a + c;
        #pragma unroll
        for (int sh = 32; sh; sh >>= 1) s += __shfl_xor(s, sh);
        float mean = s * (1.f / 128.f);
        float d0 = a - mean, d1 = c - mean;
        float v = d0 * d0 + d1 * d1;
        #pragma unroll
        for (int sh = 32; sh; sh >>= 1) v += __shfl_xor(v, sh);
        if (lane == 0) {
            stats[L]     = mean;
            stats[5 + L] = 1.f / (sqrtf(v * (1.f / 127.f)) + 1e-8f);
        }
    }
    __syncthreads();
    for (int idx = t; idx < 640; idx += 256) {
        int L = idx >> 7;
        feat[idx] = (feat[idx] - stats[L]) * stats[5 + L];
    }
    __syncthreads();

    int o = c8 * 64 + lane;
    float acc = 0.f;
    const float* wc = w + o;                   // lanes -> 256B coalesced rows
    int k0 = wv * 160;                         // 4-way K split of 640
    #pragma unroll 8
    for (int k = k0; k < k0 + 160; ++k) acc = fmaf(feat[k], wc[(size_t)k * 512], acc);
    part[t] = acc;
    __syncthreads();
    if (t < 64) {
        float r = part[t] + part[t + 64] + part[t + 128] + part[t + 192];
        h1[(size_t)n * 512 + c8 * 64 + t] = r + b[c8 * 64 + t];
    }
}

// norm(ddof=1) + leaky over 512-vector in LDS, 256 threads (2 elems/thread)
__device__ __forceinline__ void norm_leaky_512(float* buf, float* red, int t) {
    float a = buf[t], c = buf[t + 256];
    float s = a + c;
    #pragma unroll
    for (int sh = 32; sh; sh >>= 1) s += __shfl_xor(s, sh);
    if ((t & 63) == 0) red[t >> 6] = s;
    __syncthreads();
    float mean = (red[0] + red[1] + red[2] + red[3]) * (1.f / 512.f);
    float d0 = a - mean, d1 = c - mean;
    float v = d0 * d0 + d1 * d1;
    #pragma unroll
    for (int sh = 32; sh; sh >>= 1) v += __shfl_xor(v, sh);
    __syncthreads();                 // all threads done reading red (mean)
    if ((t & 63) == 0) red[t >> 6] = v;
    __syncthreads();
    float inv = 1.f / (sqrtf((red[0] + red[1] + red[2] + red[3]) * (1.f / 511.f)) + 1e-8f);
    float n0 = d0 * inv, n1 = d1 * inv;
    buf[t]       = n0 > 0.f ? n0 : 0.01f * n0;
    buf[t + 256] = n1 > 0.f ? n1 : 0.01f * n1;
    __syncthreads();
}

// fc2: 64 blocks = 8 samples x 8 output-chunks of 64
__global__ __launch_bounds__(256) void hfc2_kernel(
    const float* __restrict__ h1, const float* __restrict__ w,
    const float* __restrict__ b, float* __restrict__ h2) {
    __shared__ float buf[512];
    __shared__ float red[4];
    __shared__ float part[256];
    int blk = blockIdx.x;
    int n = blk >> 3, c8 = blk & 7;
    int t = threadIdx.x;
    buf[t]       = h1[(size_t)n * 512 + t];
    buf[t + 256] = h1[(size_t)n * 512 + t + 256];
    __syncthreads();
    norm_leaky_512(buf, red, t);
    int wv = t >> 6, lane = t & 63;
    int o = c8 * 64 + lane;
    float acc = 0.f;
    const float* wc = w + o;
    int k0 = wv * 128;
    #pragma unroll 8
    for (int k = k0; k < k0 + 128; ++k) acc = fmaf(buf[k], wc[(size_t)k * 512], acc);
    part[t] = acc;
    __syncthreads();
    if (t < 64) {
        float r = part[t] + part[t + 64] + part[t + 128] + part[t + 192];
        h2[(size_t)n * 512 + c8 * 64 + t] = r + b[c8 * 64 + t];
    }
}

// fc3: 16 blocks = 8 samples x 2 output-chunks of 64; no norm/act after
__global__ __launch_bounds__(256) void hfc3_kernel(
    const float* __restrict__ h2, const float* __restrict__ w,
    const float* __restrict__ b, float* __restrict__ out) {
    __shared__ float buf[512];
    __shared__ float red[4];
    __shared__ float part[256];
    int blk = blockIdx.x;
    int n = blk >> 1, c2 = blk & 1;
    int t = threadIdx.x;
    buf[t]       = h2[(size_t)n * 512 + t];
    buf[t + 256] = h2[(size_t)n * 512 + t + 256];
    __syncthreads();
    norm_leaky_512(buf, red, t);
    int wv = t >> 6, lane = t & 63;
    int o = c2 * 64 + lane;
    float acc = 0.f;
    const float* wc = w + o;
    int k0 = wv * 128;
    #pragma unroll 8
    for (int k = k0; k < k0 + 128; ++k) acc = fmaf(buf[k], wc[(size_t)k * 128], acc);
    part[t] = acc;
    __syncthreads();
    if (t < 64) {
        out[(size_t)n * 128 + c2 * 64 + t] =
            part[t] + part[t + 64] + part[t + 128] + part[t + 192] + b[c2 * 64 + t];
    }
}

// ----------------------------------------------------------------- launch ----
extern "C" void kernel_launch(void* const* d_in, const int* in_sizes, int n_in,
                              void* d_out, int out_size, void* d_ws, size_t ws_size,
                              hipStream_t stream) {
    static const int Cs[NLVL]   = {64, 128, 256, 512, 512};
    static const int RESs[NLVL] = {256, 128, 64, 32, 16};

    const float* x[NLVL];
    const float* w[NLVL];
    for (int i = 0; i < NLVL; ++i) {
        x[i] = (const float*)d_in[2 * i];
        w[i] = (const float*)d_in[2 * i + 1];
    }
    const float* fc1_w = (const float*)d_in[10];
    const float* fc1_b = (const float*)d_in[11];
    const float* fc2_w = (const float*)d_in[12];
    const float* fc2_b = (const float*)d_in[13];
    const float* fc3_w = (const float*)d_in[14];
    const float* fc3_b = (const float*)d_in[15];

    // workspace: smT (bf16) | quad padded fp32 | G0 | G1 | h1 | h2
    uint16_t* smT_base = (uint16_t*)d_ws;
    int smOff[NLVL];
    int off = 0;
    for (int i = 0; i < NLVL; ++i) { smOff[i] = off; off += Cs[i] * NQ; }
    size_t smBytes = (size_t)off * sizeof(uint16_t);         // 376,832 (16B mult)
    float* quad = (float*)((char*)d_ws + smBytes);
    size_t quadFloats = (size_t)NLVL * 8 * NQ * 16;          // 81,920
    float* g0 = quad + quadFloats;
    float* g1 = g0 + (size_t)8 * 64 * 64;
    float* h1 = g1 + (size_t)8 * 128 * 128;
    float* h2 = h1 + (size_t)8 * 512;
    size_t zeroBytes = (quadFloats + (size_t)8 * 64 * 64 + (size_t)8 * 128 * 128) * sizeof(float);

    SmParams sp;
    for (int i = 0; i < NLVL; ++i) {
        sp.w[i]   = w[i];
        sp.smT[i] = smT_base + smOff[i];
        sp.C[i]   = Cs[i];
    }
    softmax_kernel<<<NLVL * NQ, 64, 0, stream>>>(sp);

    hipMemsetAsync(quad, 0, zeroBytes, stream);

    GramParams gp;
    gp.x0 = x[0]; gp.x1 = x[1]; gp.g0 = g0; gp.g1 = g1;
    gram_kernel<<<768, 256, 0, stream>>>(gp);

    QuadParams qp;
    int base = 0;
    for (int i = 0; i < 3; ++i) {
        int lvl = i + 2;
        qp.x[i]   = x[lvl];
        qp.smT[i] = smT_base + smOff[lvl];
        qp.C[i]   = Cs[lvl];
        qp.HW[i]  = RESs[lvl] * RESs[lvl];
        qp.blk_base[i] = base;
        base += (RESs[lvl] * RESs[lvl] / 64) * 8;
    }
    for (int i = 3; i < NLVL; ++i) {
        qp.x[i] = nullptr; qp.smT[i] = nullptr;
        qp.C[i] = 0; qp.HW[i] = 0; qp.blk_base[i] = 0x7fffffff;
    }
    qp.quad = quad;
    quad_kernel<<<base, 256, 0, stream>>>(qp);   // base == 672

    SgsParams ssp;
    ssp.g0 = g0; ssp.g1 = g1;
    ssp.smT0 = smT_base + smOff[0];
    ssp.smT1 = smT_base + smOff[1];
    ssp.quad = quad;
    sgs_kernel<<<16, 256, 0, stream>>>(ssp);

    hfc1_kernel<<<64, 256, 0, stream>>>(quad, fc1_w, fc1_b, h1);
    hfc2_kernel<<<64, 256, 0, stream>>>(h1, fc2_w, fc2_b, h2);
    hfc3_kernel<<<16, 256, 0, stream>>>(h2, fc3_w, fc3_b, (float*)d_out);
}